// Round 2
// baseline (1316.344 us; speedup 1.0000x reference)
//
#include <hip/hip_runtime.h>

#define NB 4096
#define MD 100
#define ND 80
#define LI 10
#define NIT 20

__global__ void zero_loss_k(float* out) {
    if (threadIdx.x == 0) out[(size_t)NB * ND] = 0.f;
}

__global__ __launch_bounds__(320) void admm_k(
    const float* __restrict__ x_ini, const float* __restrict__ y,
    const float* __restrict__ H,     const float* __restrict__ xt,
    const float* __restrict__ ILb,   const float* __restrict__ tauA,
    const float* __restrict__ g1A,   const float* __restrict__ g3A,
    float* __restrict__ out)
{
    __shared__ __align__(16) float Hs[MD * ND];   // 32000 B
    __shared__ __align__(16) float ys[MD];
    __shared__ __align__(16) float Am[ND * ND];   // 25600 B
    __shared__ __align__(16) float hty[ND];
    __shared__ __align__(16) float pb[2][ND];
    __shared__ float red[8];
    __shared__ float lamS;

    const int b   = blockIdx.x;
    const int tid = threadIdx.x;

    // ---- stage H, y into LDS (coalesced float4) ----
    {
        const float4* Hg = (const float4*)(H + (size_t)b * (MD * ND));
        float4* Hl = (float4*)Hs;
        for (int k = tid; k < (MD * ND) / 4; k += 320) Hl[k] = Hg[k];
        if (tid < MD / 4)
            ((float4*)ys)[tid] = ((const float4*)(y + (size_t)b * MD))[tid];
    }
    __syncthreads();

    // ---- HTH (upper-triangle 4x4 tiles, mirrored) + HTy ----
    if (tid < 210) {
        int ti = 0, rem = tid;
        while (rem >= 20 - ti) { rem -= 20 - ti; ++ti; }
        const int tj = ti + rem;
        float acc[4][4] = {};
        for (int m = 0; m < MD; ++m) {
            const float4 a4 = *(const float4*)&Hs[m * ND + ti * 4];
            const float4 b4 = *(const float4*)&Hs[m * ND + tj * 4];
            const float av[4] = {a4.x, a4.y, a4.z, a4.w};
            const float bv[4] = {b4.x, b4.y, b4.z, b4.w};
            #pragma unroll
            for (int p = 0; p < 4; ++p)
                #pragma unroll
                for (int q = 0; q < 4; ++q)
                    acc[p][q] = fmaf(av[p], bv[q], acc[p][q]);
        }
        #pragma unroll
        for (int p = 0; p < 4; ++p)
            #pragma unroll
            for (int q = 0; q < 4; ++q) {
                Am[(ti * 4 + p) * ND + tj * 4 + q] = acc[p][q];
                Am[(tj * 4 + q) * ND + ti * 4 + p] = acc[p][q];
            }
    } else if (tid < 290) {
        const int r = tid - 210;
        float sum = 0.f;
        for (int m = 0; m < MD; ++m) sum = fmaf(Hs[m * ND + r], ys[m], sum);
        hty[r] = sum;
    }
    __syncthreads();

    // ---- Gershgorin bound: lambda_max(HTH) <= max_i sum_j |HTH[i][j]| ----
    if (tid < ND) {
        float sAbs = 0.f;
        #pragma unroll
        for (int j4 = 0; j4 < ND / 4; ++j4) {
            const float4 v = *(const float4*)&Am[tid * ND + j4 * 4];
            sAbs += fabsf(v.x) + fabsf(v.y) + fabsf(v.z) + fabsf(v.w);
        }
        pb[0][tid] = sAbs;
    }
    __syncthreads();
    if (tid == 0) {
        float mx = 0.f;
        for (int rr = 0; rr < ND; ++rr) mx = fmaxf(mx, pb[0][rr]);
        lamS = mx;
    }
    __syncthreads();

    // ---- A row-slices into registers: thread (r,s4) holds HTH[r][20*s4 .. +19] ----
    const int r  = tid >> 2;
    const int s4 = tid & 3;
    float areg[20];
    #pragma unroll
    for (int j4 = 0; j4 < 5; ++j4) {
        const float4 v = *(const float4*)&Am[r * ND + s4 * 20 + j4 * 4];
        areg[j4 * 4 + 0] = v.x; areg[j4 * 4 + 1] = v.y;
        areg[j4 * 4 + 2] = v.z; areg[j4 * 4 + 3] = v.w;
    }
    const float htyr = hty[r];
    float xr = x_ini[(size_t)b * ND + r];
    float zr = xr, ur = 0.f;
    const float lam = lamS;

    for (int ii = 0; ii < LI; ++ii) {
        const float tau = tauA[ii];
        const float ilb = ILb[ii];
        const float g1s = 0.5f / g1A[ii];
        const float g3s = 0.5f / g3A[ii];
        const float brhs = htyr + ur + tau * zr;
        // spectrum of A = HTH + tau*I  in [tau, tau + lam]
        const float delta = 0.5f * lam;
        const float theta = tau + delta;
        const float sigma = theta / delta;

        // r0 = b - A*x  (warm start from previous x)
        if (s4 == 0) pb[0][r] = xr;
        __syncthreads();
        float dsum = 0.f;
        #pragma unroll
        for (int j4 = 0; j4 < 5; ++j4) {
            const float4 v = *(const float4*)&pb[0][s4 * 20 + j4 * 4];
            dsum = fmaf(areg[j4 * 4 + 0], v.x, dsum);
            dsum = fmaf(areg[j4 * 4 + 1], v.y, dsum);
            dsum = fmaf(areg[j4 * 4 + 2], v.z, dsum);
            dsum = fmaf(areg[j4 * 4 + 3], v.w, dsum);
        }
        dsum += __shfl_xor(dsum, 1);
        dsum += __shfl_xor(dsum, 2);
        float rres = brhs - (dsum + tau * xr);
        float dk  = rres * (1.f / theta);
        float rho = delta / theta;

        for (int k = 1; k < NIT; ++k) {
            xr += dk;
            const int par = k & 1;
            if (s4 == 0) pb[par][r] = dk;
            __syncthreads();
            float ds2 = 0.f;
            #pragma unroll
            for (int j4 = 0; j4 < 5; ++j4) {
                const float4 v = *(const float4*)&pb[par][s4 * 20 + j4 * 4];
                ds2 = fmaf(areg[j4 * 4 + 0], v.x, ds2);
                ds2 = fmaf(areg[j4 * 4 + 1], v.y, ds2);
                ds2 = fmaf(areg[j4 * 4 + 2], v.z, ds2);
                ds2 = fmaf(areg[j4 * 4 + 3], v.w, ds2);
            }
            ds2 += __shfl_xor(ds2, 1);
            ds2 += __shfl_xor(ds2, 2);
            rres -= (ds2 + tau * dk);
            const float rhon = 1.f / (2.f * sigma - rho);
            dk  = rhon * (rho * dk + (2.f / delta) * rres);
            rho = rhon;
        }
        xr += dk;

        // z, u updates
        const float t = xr - ur * ilb;
        zr = tanhf(t * g1s) + tanhf((t - 2.f) * g3s) + tanhf((t + 2.f) * g3s);
        ur = fmaf(tau, zr - xr, ur);
    }

    // ---- epilogue: write x, reduce loss ----
    const float xtr = xt[(size_t)b * ND + r];
    const float dx = xr - xtr, dz = zr - xtr;
    float lv = (s4 == 0) ? (dx * dx + dz * dz) : 0.f;
    #pragma unroll
    for (int off = 1; off < 64; off <<= 1) lv += __shfl_xor(lv, off);
    if ((tid & 63) == 0) red[tid >> 6] = lv;
    __syncthreads();
    if (tid == 0)
        atomicAdd(out + (size_t)NB * ND, red[0] + red[1] + red[2] + red[3] + red[4]);
    if (s4 == 0) out[(size_t)b * ND + r] = xr;
}

extern "C" void kernel_launch(void* const* d_in, const int* in_sizes, int n_in,
                              void* d_out, int out_size, void* d_ws, size_t ws_size,
                              hipStream_t stream) {
    const float* x_ini = (const float*)d_in[0];
    const float* y     = (const float*)d_in[1];
    const float* H     = (const float*)d_in[2];
    const float* xt    = (const float*)d_in[3];
    const float* ILb   = (const float*)d_in[4];
    const float* tauA  = (const float*)d_in[5];
    const float* g1A   = (const float*)d_in[6];
    const float* g3A   = (const float*)d_in[7];
    float* out = (float*)d_out;

    zero_loss_k<<<1, 64, 0, stream>>>(out);
    admm_k<<<NB, 320, 0, stream>>>(x_ini, y, H, xt, ILb, tauA, g1A, g3A, out);
}

// Round 3
// 412.832 us; speedup vs baseline: 3.1886x; 3.1886x over previous
//
#include <hip/hip_runtime.h>

#define NB 4096
#define MD 100
#define ND 80
#define LI 10
#define NIT 14
#define MT 10   // m-rows per LDS tile

__global__ void zero_loss_k(float* out) {
    if (threadIdx.x == 0) out[(size_t)NB * ND] = 0.f;
}

__device__ __forceinline__ float fast_tanh(float a) {
    // tanh(a) = 1 - 2/(exp(2a)+1), exp via v_exp_f32 (2^x)
    float e = __builtin_amdgcn_exp2f(a * 2.885390082f);
    return 1.f - 2.f * __builtin_amdgcn_rcpf(e + 1.f);
}

__global__ __launch_bounds__(64) void admm_k(
    const float* __restrict__ x_ini, const float* __restrict__ y,
    const float* __restrict__ H,     const float* __restrict__ xt,
    const float* __restrict__ ILb,   const float* __restrict__ tauA,
    const float* __restrict__ g1A,   const float* __restrict__ g3A,
    float* __restrict__ out)
{
    __shared__ __align__(16) float Hs[MT * ND];   // 3200 B tile
    __shared__ __align__(16) float ys[MD + 4];
    __shared__ __align__(16) float xb[2][ND];     // double-buffered broadcast vec

    const int b  = blockIdx.x;
    const int l  = threadIdx.x;
    const int r0 = l >> 2;   // 0..15
    const int s4 = l & 3;    // 0..3  -> col slice [20*s4, 20*s4+20)

    // ---- stage y (100 floats) ----
    if (l < MD / 4)
        ((float4*)ys)[l] = ((const float4*)(y + (size_t)b * MD))[l];

    // ---- build HTH rows into registers + HTy, tile-by-tile ----
    float A[5][20];
    float hty[5];
    #pragma unroll
    for (int g = 0; g < 5; ++g) {
        hty[g] = 0.f;
        #pragma unroll
        for (int c = 0; c < 20; ++c) A[g][c] = 0.f;
    }

    const float* Hg = H + (size_t)b * (MD * ND);
    for (int t = 0; t < MD / MT; ++t) {
        __syncthreads();  // previous tile fully consumed (also covers ys stage at t=0)
        {
            const float4* src = (const float4*)(Hg + t * MT * ND);  // 200 float4
            float4* dst = (float4*)Hs;
            float4 v0 = src[l], v1 = src[64 + l], v2 = src[128 + l];
            dst[l] = v0; dst[64 + l] = v1; dst[128 + l] = v2;
            if (l < 8) dst[192 + l] = src[192 + l];
        }
        __syncthreads();
        #pragma unroll
        for (int mm = 0; mm < MT; ++mm) {
            const float yv = ys[t * MT + mm];
            float cv[5];
            #pragma unroll
            for (int g = 0; g < 5; ++g) cv[g] = Hs[mm * ND + r0 + 16 * g];
            #pragma unroll
            for (int j = 0; j < 5; ++j) {
                const float4 rv = *(const float4*)&Hs[mm * ND + s4 * 20 + 4 * j];
                #pragma unroll
                for (int g = 0; g < 5; ++g) {
                    A[g][4 * j + 0] = fmaf(cv[g], rv.x, A[g][4 * j + 0]);
                    A[g][4 * j + 1] = fmaf(cv[g], rv.y, A[g][4 * j + 1]);
                    A[g][4 * j + 2] = fmaf(cv[g], rv.z, A[g][4 * j + 2]);
                    A[g][4 * j + 3] = fmaf(cv[g], rv.w, A[g][4 * j + 3]);
                }
            }
            #pragma unroll
            for (int g = 0; g < 5; ++g) hty[g] = fmaf(cv[g], yv, hty[g]);
        }
    }

    // ---- Gershgorin bound on lambda_max(HTH), fully in-wave ----
    float mx;
    {
        float rs[5];
        #pragma unroll
        for (int g = 0; g < 5; ++g) {
            float s = 0.f;
            #pragma unroll
            for (int c = 0; c < 20; ++c) s += fabsf(A[g][c]);
            rs[g] = s;
        }
        #pragma unroll
        for (int g = 0; g < 5; ++g) {
            rs[g] += __shfl_xor(rs[g], 1);
            rs[g] += __shfl_xor(rs[g], 2);
        }
        mx = rs[0];
        #pragma unroll
        for (int g = 1; g < 5; ++g) mx = fmaxf(mx, rs[g]);
        #pragma unroll
        for (int off = 4; off < 64; off <<= 1) mx = fmaxf(mx, __shfl_xor(mx, off));
    }
    const float lam = mx;

    // ---- ADMM state (per-row, duplicated across the s4 quartet) ----
    float xr[5], zr[5], ur[5];
    #pragma unroll
    for (int g = 0; g < 5; ++g) {
        const float v = x_ini[(size_t)b * ND + r0 + 16 * g];
        xr[g] = v; zr[g] = v; ur[g] = 0.f;
    }

    int par = 0;
    // matvec: acc[g] = (HTH * xb[par])[r0+16g]
    auto matvec = [&](float (&acc)[5]) {
        const float* xp = &xb[par][0];
        #pragma unroll
        for (int g = 0; g < 5; ++g) acc[g] = 0.f;
        #pragma unroll
        for (int j = 0; j < 5; ++j) {
            const float4 v = *(const float4*)&xp[s4 * 20 + 4 * j];
            #pragma unroll
            for (int g = 0; g < 5; ++g) {
                acc[g] = fmaf(A[g][4 * j + 0], v.x, acc[g]);
                acc[g] = fmaf(A[g][4 * j + 1], v.y, acc[g]);
                acc[g] = fmaf(A[g][4 * j + 2], v.z, acc[g]);
                acc[g] = fmaf(A[g][4 * j + 3], v.w, acc[g]);
            }
        }
        #pragma unroll
        for (int g = 0; g < 5; ++g) {
            acc[g] += __shfl_xor(acc[g], 1);
            acc[g] += __shfl_xor(acc[g], 2);
        }
    };

    for (int ii = 0; ii < LI; ++ii) {
        const float tau = tauA[ii];
        const float ilb = ILb[ii];
        const float g1s = 0.5f / g1A[ii];
        const float g3s = 0.5f / g3A[ii];
        const float delta = 0.5f * lam;
        const float theta = tau + delta;
        const float sigma = theta / delta;
        const float invth = 1.f / theta;
        const float twod  = 2.f / delta;

        float rres[5], dk[5], acc[5];

        // r0 = b - A*x (warm start)
        if (s4 == 0) {
            #pragma unroll
            for (int g = 0; g < 5; ++g) xb[par][r0 + 16 * g] = xr[g];
        }
        __syncthreads();
        matvec(acc);
        #pragma unroll
        for (int g = 0; g < 5; ++g) {
            rres[g] = (hty[g] + ur[g] + tau * zr[g]) - (acc[g] + tau * xr[g]);
            dk[g] = rres[g] * invth;
        }
        par ^= 1;
        float rho = delta / theta;

        for (int k = 1; k < NIT; ++k) {
            #pragma unroll
            for (int g = 0; g < 5; ++g) xr[g] += dk[g];
            if (s4 == 0) {
                #pragma unroll
                for (int g = 0; g < 5; ++g) xb[par][r0 + 16 * g] = dk[g];
            }
            __syncthreads();
            matvec(acc);
            #pragma unroll
            for (int g = 0; g < 5; ++g) rres[g] -= acc[g] + tau * dk[g];
            const float rhon = 1.f / (2.f * sigma - rho);
            #pragma unroll
            for (int g = 0; g < 5; ++g) dk[g] = rhon * (rho * dk[g] + twod * rres[g]);
            rho = rhon;
            par ^= 1;
        }
        #pragma unroll
        for (int g = 0; g < 5; ++g) xr[g] += dk[g];

        // z, u updates
        #pragma unroll
        for (int g = 0; g < 5; ++g) {
            const float tt = xr[g] - ur[g] * ilb;
            zr[g] = fast_tanh(tt * g1s) + fast_tanh((tt - 2.f) * g3s)
                  + fast_tanh((tt + 2.f) * g3s);
            ur[g] = fmaf(tau, zr[g] - xr[g], ur[g]);
        }
    }

    // ---- epilogue: x out + loss reduce (in-wave) ----
    float lv = 0.f;
    #pragma unroll
    for (int g = 0; g < 5; ++g) {
        const float xtr = xt[(size_t)b * ND + r0 + 16 * g];
        const float dx = xr[g] - xtr, dz = zr[g] - xtr;
        lv += dx * dx + dz * dz;
        if (s4 == 0) out[(size_t)b * ND + r0 + 16 * g] = xr[g];
    }
    if (s4 != 0) lv = 0.f;
    #pragma unroll
    for (int off = 1; off < 64; off <<= 1) lv += __shfl_xor(lv, off);
    if (l == 0) atomicAdd(out + (size_t)NB * ND, lv);
}

extern "C" void kernel_launch(void* const* d_in, const int* in_sizes, int n_in,
                              void* d_out, int out_size, void* d_ws, size_t ws_size,
                              hipStream_t stream) {
    const float* x_ini = (const float*)d_in[0];
    const float* y     = (const float*)d_in[1];
    const float* H     = (const float*)d_in[2];
    const float* xt    = (const float*)d_in[3];
    const float* ILb   = (const float*)d_in[4];
    const float* tauA  = (const float*)d_in[5];
    const float* g1A   = (const float*)d_in[6];
    const float* g3A   = (const float*)d_in[7];
    float* out = (float*)d_out;

    zero_loss_k<<<1, 64, 0, stream>>>(out);
    admm_k<<<NB, 64, 0, stream>>>(x_ini, y, H, xt, ILb, tauA, g1A, g3A, out);
}

// Round 7
// 366.560 us; speedup vs baseline: 3.5911x; 1.1262x over previous
//
#include <hip/hip_runtime.h>

#define NB 4096
#define MD 100
#define ND 80
#define LI 10
#define NIT 10
#define MT 10   // m-rows per LDS tile

__global__ void zero_loss_k(float* out) {
    if (threadIdx.x == 0) out[(size_t)NB * ND] = 0.f;
}

__device__ __forceinline__ float fast_tanh(float a) {
    // tanh(a) = 1 - 2/(exp(2a)+1), exp via v_exp_f32 (2^x)
    float e = __builtin_amdgcn_exp2f(a * 2.885390082f);
    return 1.f - 2.f * __builtin_amdgcn_rcpf(e + 1.f);
}

__global__ __launch_bounds__(64, 1) void admm_k(
    const float* __restrict__ x_ini, const float* __restrict__ y,
    const float* __restrict__ H,     const float* __restrict__ xt,
    const float* __restrict__ ILb,   const float* __restrict__ tauA,
    const float* __restrict__ g1A,   const float* __restrict__ g3A,
    float* __restrict__ out)
{
    __shared__ __align__(16) float Hs[MT * ND];   // 3200 B tile
    __shared__ __align__(16) float ys[MD + 4];
    __shared__ __align__(16) float xb[2][ND];     // double-buffered broadcast vec

    const int b  = blockIdx.x;
    const int l  = threadIdx.x;
    const int r0 = l >> 2;   // 0..15
    const int s4 = l & 3;    // 0..3  -> col slice [20*s4, 20*s4+20)

    // ---- stage y (100 floats) ----
    if (l < MD / 4)
        ((float4*)ys)[l] = ((const float4*)(y + (size_t)b * MD))[l];

    // ---- build HTH rows into registers + HTy, tile-by-tile ----
    float A[5][20];
    float hty[5];
    #pragma unroll
    for (int g = 0; g < 5; ++g) {
        hty[g] = 0.f;
        #pragma unroll
        for (int c = 0; c < 20; ++c) A[g][c] = 0.f;
    }

    const float* Hg = H + (size_t)b * (MD * ND);
    for (int t = 0; t < MD / MT; ++t) {
        __syncthreads();  // previous tile fully consumed (also covers ys stage at t=0)
        {
            const float4* src = (const float4*)(Hg + t * MT * ND);  // 200 float4
            float4* dst = (float4*)Hs;
            float4 v0 = src[l], v1 = src[64 + l], v2 = src[128 + l];
            dst[l] = v0; dst[64 + l] = v1; dst[128 + l] = v2;
            if (l < 8) dst[192 + l] = src[192 + l];
        }
        __syncthreads();
        #pragma unroll
        for (int mm = 0; mm < MT; ++mm) {
            const float yv = ys[t * MT + mm];
            float cv[5];
            #pragma unroll
            for (int g = 0; g < 5; ++g) cv[g] = Hs[mm * ND + r0 + 16 * g];
            #pragma unroll
            for (int j = 0; j < 5; ++j) {
                const float4 rv = *(const float4*)&Hs[mm * ND + s4 * 20 + 4 * j];
                #pragma unroll
                for (int g = 0; g < 5; ++g) {
                    A[g][4 * j + 0] = fmaf(cv[g], rv.x, A[g][4 * j + 0]);
                    A[g][4 * j + 1] = fmaf(cv[g], rv.y, A[g][4 * j + 1]);
                    A[g][4 * j + 2] = fmaf(cv[g], rv.z, A[g][4 * j + 2]);
                    A[g][4 * j + 3] = fmaf(cv[g], rv.w, A[g][4 * j + 3]);
                }
            }
            #pragma unroll
            for (int g = 0; g < 5; ++g) hty[g] = fmaf(cv[g], yv, hty[g]);
        }
    }

    // ---- Gershgorin bound on lambda_max(HTH), fully in-wave ----
    float mx;
    {
        float rs[5];
        #pragma unroll
        for (int g = 0; g < 5; ++g) {
            float s = 0.f;
            #pragma unroll
            for (int c = 0; c < 20; ++c) s += fabsf(A[g][c]);
            rs[g] = s;
        }
        #pragma unroll
        for (int g = 0; g < 5; ++g) {
            rs[g] += __shfl_xor(rs[g], 1);
            rs[g] += __shfl_xor(rs[g], 2);
        }
        mx = rs[0];
        #pragma unroll
        for (int g = 1; g < 5; ++g) mx = fmaxf(mx, rs[g]);
        #pragma unroll
        for (int off = 4; off < 64; off <<= 1) mx = fmaxf(mx, __shfl_xor(mx, off));
    }
    const float lam = mx;

    // ---- ADMM state (per-row, duplicated across the s4 quartet) ----
    float xr[5], zr[5], ur[5];
    #pragma unroll
    for (int g = 0; g < 5; ++g) {
        const float v = x_ini[(size_t)b * ND + r0 + 16 * g];
        xr[g] = v; zr[g] = v; ur[g] = 0.f;
    }

    int par = 0;
    // matvec: acc[g] = (HTH * xb[par])[r0+16g]
    auto matvec = [&](float (&acc)[5]) {
        const float* xp = &xb[par][0];
        {
            const float4 v = *(const float4*)&xp[s4 * 20];
            #pragma unroll
            for (int g = 0; g < 5; ++g)
                acc[g] = fmaf(A[g][3], v.w, fmaf(A[g][2], v.z,
                         fmaf(A[g][1], v.y, A[g][0] * v.x)));
        }
        #pragma unroll
        for (int j = 1; j < 5; ++j) {
            const float4 v = *(const float4*)&xp[s4 * 20 + 4 * j];
            #pragma unroll
            for (int g = 0; g < 5; ++g) {
                acc[g] = fmaf(A[g][4 * j + 0], v.x, acc[g]);
                acc[g] = fmaf(A[g][4 * j + 1], v.y, acc[g]);
                acc[g] = fmaf(A[g][4 * j + 2], v.z, acc[g]);
                acc[g] = fmaf(A[g][4 * j + 3], v.w, acc[g]);
            }
        }
        #pragma unroll
        for (int g = 0; g < 5; ++g) {
            acc[g] += __shfl_xor(acc[g], 1);
            acc[g] += __shfl_xor(acc[g], 2);
        }
    };

    for (int ii = 0; ii < LI; ++ii) {
        const float tau = tauA[ii];
        const float ilb = ILb[ii];
        const float g1s = 0.5f / g1A[ii];
        const float g3s = 0.5f / g3A[ii];
        const float delta = 0.5f * lam;
        const float theta = tau + delta;
        const float sigma = theta / delta;
        const float invth = 1.f / theta;
        const float twod  = 2.f / delta;

        float rres[5], dk[5], acc[5];

        // r0 = b - A*x (warm start)
        if (s4 == 0) {
            #pragma unroll
            for (int g = 0; g < 5; ++g) xb[par][r0 + 16 * g] = xr[g];
        }
        __syncthreads();
        matvec(acc);
        #pragma unroll
        for (int g = 0; g < 5; ++g) {
            rres[g] = (hty[g] + ur[g] + tau * zr[g]) - (acc[g] + tau * xr[g]);
            dk[g] = rres[g] * invth;
        }
        par ^= 1;
        float rho = delta / theta;

        for (int k = 1; k < NIT; ++k) {
            #pragma unroll
            for (int g = 0; g < 5; ++g) xr[g] += dk[g];
            if (s4 == 0) {
                #pragma unroll
                for (int g = 0; g < 5; ++g) xb[par][r0 + 16 * g] = dk[g];
            }
            __syncthreads();
            matvec(acc);
            #pragma unroll
            for (int g = 0; g < 5; ++g) rres[g] -= acc[g] + tau * dk[g];
            const float rhon = 1.f / (2.f * sigma - rho);
            #pragma unroll
            for (int g = 0; g < 5; ++g) dk[g] = rhon * (rho * dk[g] + twod * rres[g]);
            rho = rhon;
            par ^= 1;
        }
        #pragma unroll
        for (int g = 0; g < 5; ++g) xr[g] += dk[g];

        // z, u updates
        #pragma unroll
        for (int g = 0; g < 5; ++g) {
            const float tt = xr[g] - ur[g] * ilb;
            zr[g] = fast_tanh(tt * g1s) + fast_tanh((tt - 2.f) * g3s)
                  + fast_tanh((tt + 2.f) * g3s);
            ur[g] = fmaf(tau, zr[g] - xr[g], ur[g]);
        }
    }

    // ---- epilogue: x out + loss reduce (in-wave) ----
    float lv = 0.f;
    #pragma unroll
    for (int g = 0; g < 5; ++g) {
        const float xtr = xt[(size_t)b * ND + r0 + 16 * g];
        const float dx = xr[g] - xtr, dz = zr[g] - xtr;
        lv += dx * dx + dz * dz;
        if (s4 == 0) out[(size_t)b * ND + r0 + 16 * g] = xr[g];
    }
    if (s4 != 0) lv = 0.f;
    #pragma unroll
    for (int off = 1; off < 64; off <<= 1) lv += __shfl_xor(lv, off);
    if (l == 0) atomicAdd(out + (size_t)NB * ND, lv);
}

extern "C" void kernel_launch(void* const* d_in, const int* in_sizes, int n_in,
                              void* d_out, int out_size, void* d_ws, size_t ws_size,
                              hipStream_t stream) {
    const float* x_ini = (const float*)d_in[0];
    const float* y     = (const float*)d_in[1];
    const float* H     = (const float*)d_in[2];
    const float* xt    = (const float*)d_in[3];
    const float* ILb   = (const float*)d_in[4];
    const float* tauA  = (const float*)d_in[5];
    const float* g1A   = (const float*)d_in[6];
    const float* g3A   = (const float*)d_in[7];
    float* out = (float*)d_out;

    zero_loss_k<<<1, 64, 0, stream>>>(out);
    admm_k<<<NB, 64, 0, stream>>>(x_ini, y, H, xt, ILb, tauA, g1A, g3A, out);
}